// Round 1
// baseline (383.183 us; speedup 1.0000x reference)
//
#include <hip/hip_runtime.h>

// Sparse Clebsch-Gordan tensor product, LMAX=3.
// out[b, mu3[k], c] += cg[k] * x[b, mu1[k], c] * y[b, mu2[k], c]
// B=1024, D_IN=16, D_OUT=156, C=128.
//
// The index pattern (mu1,mu2,mu3) is deterministic (same loops as the Python
// reference builder); only cg values are data. We rebuild the indices as
// constexpr arrays so the fully-unrolled K-loop has compile-time indices into
// the register arrays xv[16]/yv[16]/acc[156] (avoids scratch — runtime-indexed
// register arrays spill to local memory).

#define LMAX_ 3
#define D_IN_ 16
#define D_OUT_ 156
#define C_ 128
#define KMAX_ 8192

struct CGIdx {
    int n;
    int mu1[KMAX_];
    int mu2[KMAX_];
    int mu3[KMAX_];
};

constexpr CGIdx build_cg() {
    CGIdx t{};
    const int off_in[4] = {0, 1, 4, 9};
    int off3 = 0;
    int n = 0;
    for (int l1 = 0; l1 <= LMAX_; ++l1) {
        for (int l2 = 0; l2 <= LMAX_; ++l2) {
            int lo = l1 > l2 ? l1 - l2 : l2 - l1;
            int hi = (l1 + l2) < LMAX_ ? (l1 + l2) : LMAX_;
            for (int l3 = lo; l3 <= hi; ++l3) {
                for (int m1 = 0; m1 < 2 * l1 + 1; ++m1) {
                    for (int m2 = 0; m2 < 2 * l2 + 1; ++m2) {
                        int a = m1 - l1, b = m2 - l2;
                        for (int m3 = 0; m3 < 2 * l3 + 1; ++m3) {
                            int c = m3 - l3;
                            int s = a + b; if (s < 0) s = -s;
                            int d = a - b; if (d < 0) d = -d;
                            int e = c < 0 ? -c : c;
                            if (s == e || d == e) {
                                t.mu1[n] = off_in[l1] + m1;
                                t.mu2[n] = off_in[l2] + m2;
                                t.mu3[n] = off3 + m3;
                                ++n;
                            }
                        }
                    }
                }
                off3 += 2 * l3 + 1;
            }
        }
    }
    t.n = n;
    return t;
}

constexpr CGIdx CG = build_cg();
constexpr int K = CG.n;

__global__ __launch_bounds__(256, 2) void tp_cg_kernel(
    const float* __restrict__ x, const float* __restrict__ y,
    const float* __restrict__ cg, float* __restrict__ out) {
    const int c = threadIdx.x & (C_ - 1);
    const int b = (blockIdx.x << 1) | (threadIdx.x >> 7);

    const float* xb = x + (size_t)b * (D_IN_ * C_) + c;
    const float* yb = y + (size_t)b * (D_IN_ * C_) + c;

    float xv[D_IN_], yv[D_IN_];
#pragma unroll
    for (int i = 0; i < D_IN_; ++i) {
        xv[i] = xb[i * C_];
        yv[i] = yb[i * C_];
    }

    float acc[D_OUT_];
#pragma unroll
    for (int j = 0; j < D_OUT_; ++j) acc[j] = 0.0f;

#pragma unroll
    for (int k = 0; k < K; ++k) {
        acc[CG.mu3[k]] = fmaf(cg[k], xv[CG.mu1[k]] * yv[CG.mu2[k]], acc[CG.mu3[k]]);
    }

    float* ob = out + (size_t)b * (D_OUT_ * C_) + c;
#pragma unroll
    for (int j = 0; j < D_OUT_; ++j) ob[j * C_] = acc[j];
}

extern "C" void kernel_launch(void* const* d_in, const int* in_sizes, int n_in,
                              void* d_out, int out_size, void* d_ws, size_t ws_size,
                              hipStream_t stream) {
    const float* x  = (const float*)d_in[0];
    const float* y  = (const float*)d_in[1];
    const float* cg = (const float*)d_in[2];
    float* out = (float*)d_out;

    const int B = in_sizes[0] / (D_IN_ * C_);
    const int nblocks = (B * C_) / 256;  // 2 b-rows per 256-thread block

    tp_cg_kernel<<<nblocks, 256, 0, stream>>>(x, y, cg, out);
}

// Round 2
// 111.882 us; speedup vs baseline: 3.4249x; 3.4249x over previous
//
#include <hip/hip_runtime.h>
#include <utility>

// Sparse Clebsch-Gordan tensor product, LMAX=3.
// out[b, mu3[k], c] += cg[k] * x[b, mu1[k], c] * y[b, mu2[k], c]
// B=1024, D_IN=16, D_OUT=156, C=128, K=1260 terms.
//
// R1 lesson: a #pragma unroll over K=1260 was declined by the compiler ->
// runtime indices -> xv/yv/acc spilled to scratch (VGPR_Count=32, 3.5x HBM
// traffic). Fix: group terms by output row (constexpr counting sort) and emit
// the computation via fold expressions, so every index is a compile-time
// constant and no acc[] array exists at all (one scalar sum per row, stored
// immediately). Register pressure ~ xv[16]+yv[16]+scalar.

#define D_IN_ 16
#define D_OUT_ 156
#define C_ 128
#define KMAX_ 2048

struct CGRows {
    int n;
    int start[D_OUT_ + 1];  // row start offsets into k/m1/m2
    int k[KMAX_];           // original term index (for cg[] lookup)
    int m1[KMAX_];
    int m2[KMAX_];
};

constexpr CGRows build_rows() {
    // First pass: generate terms in the reference's k order.
    int mu1[KMAX_] = {}, mu2[KMAX_] = {}, mu3[KMAX_] = {};
    int n = 0;
    const int off_in[4] = {0, 1, 4, 9};
    int off3 = 0;
    for (int l1 = 0; l1 <= 3; ++l1) {
        for (int l2 = 0; l2 <= 3; ++l2) {
            int lo = l1 > l2 ? l1 - l2 : l2 - l1;
            int hi = (l1 + l2) < 3 ? (l1 + l2) : 3;
            for (int l3 = lo; l3 <= hi; ++l3) {
                for (int m1 = 0; m1 < 2 * l1 + 1; ++m1) {
                    for (int m2 = 0; m2 < 2 * l2 + 1; ++m2) {
                        int a = m1 - l1, b = m2 - l2;
                        for (int m3 = 0; m3 < 2 * l3 + 1; ++m3) {
                            int c = m3 - l3;
                            int s = a + b; if (s < 0) s = -s;
                            int d = a - b; if (d < 0) d = -d;
                            int e = c < 0 ? -c : c;
                            if (s == e || d == e) {
                                mu1[n] = off_in[l1] + m1;
                                mu2[n] = off_in[l2] + m2;
                                mu3[n] = off3 + m3;
                                ++n;
                            }
                        }
                    }
                }
                off3 += 2 * l3 + 1;
            }
        }
    }
    // Counting sort by mu3 (row).
    CGRows r{};
    r.n = n;
    int cnt[D_OUT_] = {};
    for (int i = 0; i < n; ++i) cnt[mu3[i]]++;
    r.start[0] = 0;
    for (int j = 0; j < D_OUT_; ++j) r.start[j + 1] = r.start[j] + cnt[j];
    int pos[D_OUT_] = {};
    for (int j = 0; j < D_OUT_; ++j) pos[j] = r.start[j];
    for (int i = 0; i < n; ++i) {
        int j = mu3[i];
        int p = pos[j]++;
        r.k[p] = i;
        r.m1[p] = mu1[i];
        r.m2[p] = mu2[i];
    }
    return r;
}

constexpr CGRows CG = build_rows();

template <int Base, int... Ts>
__device__ __forceinline__ float row_sum_impl(const float* __restrict__ cg,
                                              const float (&xv)[D_IN_],
                                              const float (&yv)[D_IN_],
                                              std::integer_sequence<int, Ts...>) {
    float s = 0.0f;
    ((s = fmaf(cg[CG.k[Base + Ts]], xv[CG.m1[Base + Ts]] * yv[CG.m2[Base + Ts]], s)), ...);
    return s;
}

template <int J>
__device__ __forceinline__ float row_sum(const float* __restrict__ cg,
                                         const float (&xv)[D_IN_],
                                         const float (&yv)[D_IN_]) {
    constexpr int base = CG.start[J];
    constexpr int nt = CG.start[J + 1] - CG.start[J];
    return row_sum_impl<base>(cg, xv, yv, std::make_integer_sequence<int, nt>{});
}

template <int... Js>
__device__ __forceinline__ void all_rows(float* __restrict__ ob,
                                         const float* __restrict__ cg,
                                         const float (&xv)[D_IN_],
                                         const float (&yv)[D_IN_],
                                         std::integer_sequence<int, Js...>) {
    ((ob[Js * C_] = row_sum<Js>(cg, xv, yv)), ...);
}

__global__ __launch_bounds__(256) void tp_cg_kernel(
    const float* __restrict__ x, const float* __restrict__ y,
    const float* __restrict__ cg, float* __restrict__ out) {
    const int c = threadIdx.x & (C_ - 1);
    const int b = (int)((blockIdx.x << 1) | (threadIdx.x >> 7));

    const float* xb = x + (size_t)b * (D_IN_ * C_) + c;
    const float* yb = y + (size_t)b * (D_IN_ * C_) + c;

    float xv[D_IN_], yv[D_IN_];
#pragma unroll
    for (int i = 0; i < D_IN_; ++i) {
        xv[i] = xb[i * C_];
        yv[i] = yb[i * C_];
    }

    float* ob = out + (size_t)b * (D_OUT_ * C_) + c;
    all_rows(ob, cg, xv, yv, std::make_integer_sequence<int, D_OUT_>{});
}

extern "C" void kernel_launch(void* const* d_in, const int* in_sizes, int n_in,
                              void* d_out, int out_size, void* d_ws, size_t ws_size,
                              hipStream_t stream) {
    const float* x  = (const float*)d_in[0];
    const float* y  = (const float*)d_in[1];
    const float* cg = (const float*)d_in[2];
    float* out = (float*)d_out;

    const int B = in_sizes[0] / (D_IN_ * C_);
    const int nblocks = (B * C_) / 256;  // 2 batch rows per 256-thread block

    tp_cg_kernel<<<nblocks, 256, 0, stream>>>(x, y, cg, out);
}

// Round 3
// 109.507 us; speedup vs baseline: 3.4992x; 1.0217x over previous
//
#include <hip/hip_runtime.h>
#include <utility>

// Sparse Clebsch-Gordan tensor product, LMAX=3.
// out[b, mu3[k], c] += cg[k] * x[b, mu1[k], c] * y[b, mu2[k], c]
// B=1024, D_IN=16, D_OUT=156, C=128, K~1260 terms.
//
// R2 lesson: row-sorted term order makes cg[] offsets scattered -> ~1260
// unmergeable s_load_dword per thread -> SMEM batch stalls. R3: (1) pre-gather
// cg into row-sorted order in d_ws so the hot kernel reads CONSECUTIVE scalar
// offsets (merged s_load_dwordx4/x8); (2) float2 over C to halve VMEM inst
// count; (3) split output rows across 2 threads per (b,c2) to keep 2048 waves
// (2/SIMD) for latency hiding. All indices remain compile-time constants
// (fold expressions) so nothing spills to scratch.

#define D_IN_ 16
#define D_OUT_ 156
#define C_ 128
#define KMAX_ 2048

struct CGRows {
    int n;
    int start[D_OUT_ + 1];  // row start offsets
    int k[KMAX_];           // original term index (for the gather)
    int m1[KMAX_];
    int m2[KMAX_];
};

constexpr CGRows build_rows() {
    int mu1[KMAX_] = {}, mu2[KMAX_] = {}, mu3[KMAX_] = {};
    int n = 0;
    const int off_in[4] = {0, 1, 4, 9};
    int off3 = 0;
    for (int l1 = 0; l1 <= 3; ++l1) {
        for (int l2 = 0; l2 <= 3; ++l2) {
            int lo = l1 > l2 ? l1 - l2 : l2 - l1;
            int hi = (l1 + l2) < 3 ? (l1 + l2) : 3;
            for (int l3 = lo; l3 <= hi; ++l3) {
                for (int m1 = 0; m1 < 2 * l1 + 1; ++m1) {
                    for (int m2 = 0; m2 < 2 * l2 + 1; ++m2) {
                        int a = m1 - l1, b = m2 - l2;
                        for (int m3 = 0; m3 < 2 * l3 + 1; ++m3) {
                            int c = m3 - l3;
                            int s = a + b; if (s < 0) s = -s;
                            int d = a - b; if (d < 0) d = -d;
                            int e = c < 0 ? -c : c;
                            if (s == e || d == e) {
                                mu1[n] = off_in[l1] + m1;
                                mu2[n] = off_in[l2] + m2;
                                mu3[n] = off3 + m3;
                                ++n;
                            }
                        }
                    }
                }
                off3 += 2 * l3 + 1;
            }
        }
    }
    CGRows r{};
    r.n = n;
    int cnt[D_OUT_] = {};
    for (int i = 0; i < n; ++i) cnt[mu3[i]]++;
    r.start[0] = 0;
    for (int j = 0; j < D_OUT_; ++j) r.start[j + 1] = r.start[j] + cnt[j];
    int pos[D_OUT_] = {};
    for (int j = 0; j < D_OUT_; ++j) pos[j] = r.start[j];
    for (int i = 0; i < n; ++i) {
        int j = mu3[i];
        int p = pos[j]++;
        r.k[p] = i;
        r.m1[p] = mu1[i];
        r.m2[p] = mu2[i];
    }
    return r;
}

constexpr CGRows CG = build_rows();
constexpr int K = CG.n;
static_assert(K <= KMAX_, "KMAX too small");

// Row split point: first row index whose start offset reaches half the terms.
constexpr int find_split() {
    int j = 0;
    while (CG.start[j] < CG.n / 2) ++j;
    return j;
}
constexpr int RSPLIT = find_split();

constexpr unsigned need1(int j0, int j1) {
    unsigned m = 0;
    for (int p = CG.start[j0]; p < CG.start[j1]; ++p) m |= 1u << CG.m1[p];
    return m;
}
constexpr unsigned need2(int j0, int j1) {
    unsigned m = 0;
    for (int p = CG.start[j0]; p < CG.start[j1]; ++p) m |= 1u << CG.m2[p];
    return m;
}

// Device copy of the gather indices (runtime-indexed -> must live in memory).
__device__ __constant__ CGRows dCG = build_rows();

__global__ void gather_cg(const float* __restrict__ cg, float* __restrict__ cgs) {
    int i = blockIdx.x * 256 + threadIdx.x;
    if (i < K) cgs[i] = cg[dCG.k[i]];
}

template <unsigned M, int I>
__device__ __forceinline__ void load1(float2 (&v)[D_IN_], const float* __restrict__ base) {
    if constexpr ((M >> I) & 1u) v[I] = *(const float2*)(base + I * C_);
    else v[I] = make_float2(0.0f, 0.0f);
}

template <unsigned M, int... Is>
__device__ __forceinline__ void load_masked(float2 (&v)[D_IN_], const float* __restrict__ base,
                                            std::integer_sequence<int, Is...>) {
    (load1<M, Is>(v, base), ...);
}

template <int Base, int... Ts>
__device__ __forceinline__ float2 row_sum2(const float* __restrict__ cgs,
                                           const float2 (&xv)[D_IN_],
                                           const float2 (&yv)[D_IN_],
                                           std::integer_sequence<int, Ts...>) {
    float2 s = make_float2(0.0f, 0.0f);
    (((s.x = fmaf(cgs[Base + Ts], xv[CG.m1[Base + Ts]].x * yv[CG.m2[Base + Ts]].x, s.x)),
      (s.y = fmaf(cgs[Base + Ts], xv[CG.m1[Base + Ts]].y * yv[CG.m2[Base + Ts]].y, s.y))), ...);
    return s;
}

template <int J>
__device__ __forceinline__ void store_row(float* __restrict__ ob, const float* __restrict__ cgs,
                                          const float2 (&xv)[D_IN_], const float2 (&yv)[D_IN_]) {
    constexpr int base = CG.start[J];
    constexpr int nt = CG.start[J + 1] - CG.start[J];
    float2 s = row_sum2<base>(cgs, xv, yv, std::make_integer_sequence<int, nt>{});
    *(float2*)(ob + J * C_) = s;
}

template <int J0, int... Js>
__device__ __forceinline__ void rows_range(float* __restrict__ ob, const float* __restrict__ cgs,
                                           const float2 (&xv)[D_IN_], const float2 (&yv)[D_IN_],
                                           std::integer_sequence<int, Js...>) {
    (store_row<J0 + Js>(ob, cgs, xv, yv), ...);
}

__global__ __launch_bounds__(256, 2) void tp_cg_kernel(
    const float* __restrict__ x, const float* __restrict__ y,
    const float* __restrict__ cgs, float* __restrict__ out) {
    const int tid = (int)threadIdx.x;
    const int c2 = tid & 63;             // float2 column index (64 per row)
    const int half = (tid >> 6) & 1;     // which row-range this wave handles
    const int b = (int)((blockIdx.x << 1) | (tid >> 7));

    const float* xb = x + (size_t)b * (D_IN_ * C_) + c2 * 2;
    const float* yb = y + (size_t)b * (D_IN_ * C_) + c2 * 2;
    float* ob = out + (size_t)b * (D_OUT_ * C_) + c2 * 2;

    float2 xv[D_IN_], yv[D_IN_];
    if (half == 0) {
        constexpr unsigned m1 = need1(0, RSPLIT), m2 = need2(0, RSPLIT);
        load_masked<m1>(xv, xb, std::make_integer_sequence<int, D_IN_>{});
        load_masked<m2>(yv, yb, std::make_integer_sequence<int, D_IN_>{});
        rows_range<0>(ob, cgs, xv, yv, std::make_integer_sequence<int, RSPLIT>{});
    } else {
        constexpr unsigned m1 = need1(RSPLIT, D_OUT_), m2 = need2(RSPLIT, D_OUT_);
        load_masked<m1>(xv, xb, std::make_integer_sequence<int, D_IN_>{});
        load_masked<m2>(yv, yb, std::make_integer_sequence<int, D_IN_>{});
        rows_range<RSPLIT>(ob, cgs, xv, yv, std::make_integer_sequence<int, D_OUT_ - RSPLIT>{});
    }
}

extern "C" void kernel_launch(void* const* d_in, const int* in_sizes, int n_in,
                              void* d_out, int out_size, void* d_ws, size_t ws_size,
                              hipStream_t stream) {
    const float* x  = (const float*)d_in[0];
    const float* y  = (const float*)d_in[1];
    const float* cg = (const float*)d_in[2];
    float* out = (float*)d_out;
    float* cgs = (float*)d_ws;  // K floats of row-sorted coefficients

    const int B = in_sizes[0] / (D_IN_ * C_);

    gather_cg<<<(K + 255) / 256, 256, 0, stream>>>(cg, cgs);

    // threads = B * (C/2 float2 lanes) * 2 row-halves; 2 batch rows per block
    const int nblocks = B / 2;
    tp_cg_kernel<<<nblocks, 256, 0, stream>>>(x, y, cgs, out);
}